// Round 4
// baseline (164.430 us; speedup 1.0000x reference)
//
#include <hip/hip_runtime.h>

// SConv2dAvg: out[b,o,y,x] = sum_{c,kh,kw} in[b,c,2y+selh+kh,2x+selw+kw] * W[o,c,kh,kw] + bias[o]
// B=16 Cin=64 H=W=128 Cout=64 oh=ow=63 stride=2, fp32 in/out.
// Round 4: stage 1 = NCHW->NHWC repack + fp32->bf16 cast. Stage 2 = LDS-free
// MFMA implicit GEMM: each lane loads its 16B A/B fragments DIRECTLY from
// global (NHWC / (o,tap,c) weights are fragment-contiguous), no staging
// barriers; LDS used only for the output transpose epilogue.

#define B_    16
#define CIN   64
#define H_    128
#define W_    128
#define COUT  64
#define OH    63
#define OW    63
#define NPIX  (OH * OW)      // 3969
#define KTOT  (CIN * 9)      // 576

typedef short  short8  __attribute__((ext_vector_type(8)));
typedef float  float4v __attribute__((ext_vector_type(4)));

__device__ inline short f2bf(float f) {     // RN-to-even fp32 -> bf16 bits
    union { float f; unsigned u; } x; x.f = f;
    unsigned r = x.u + 0x7fffu + ((x.u >> 16) & 1u);
    return (short)(r >> 16);
}

// ---------------- stage 1a: input NCHW fp32 -> NHWC bf16 ----------------
__global__ __launch_bounds__(256)
void transpose_nhwc_bf16(const float* __restrict__ in, short* __restrict__ nhwc) {
    __shared__ float T[64 * 65];            // T[c][w], pad 65
    const int tid = threadIdx.x;
    const int w0  = blockIdx.x * 64;
    const int h   = blockIdx.y;
    const int b   = blockIdx.z;

    {   // load 64c x 64w, coalesced along w
        const int w4 = tid & 15;
        const int cl = tid >> 4;
#pragma unroll
        for (int i = 0; i < 4; ++i) {
            const int c = cl + 16 * i;
            const float4 v = *(const float4*)&in[((b * CIN + c) * H_ + h) * W_ + w0 + 4 * w4];
            T[c * 65 + 4 * w4 + 0] = v.x;
            T[c * 65 + 4 * w4 + 1] = v.y;
            T[c * 65 + 4 * w4 + 2] = v.z;
            T[c * 65 + 4 * w4 + 3] = v.w;
        }
    }
    __syncthreads();
    {   // store: 8 channels/thread as one 16B bf16 vector, coalesced along c
        const int cg = tid & 7;             // channel group (8 ch)
        const int wl = tid >> 3;            // 0..31
#pragma unroll
        for (int i = 0; i < 2; ++i) {
            const int w = wl + 32 * i;
            short8 v;
#pragma unroll
            for (int t = 0; t < 8; ++t)
                v[t] = f2bf(T[(8 * cg + t) * 65 + w]);
            *(short8*)&nhwc[((b * H_ + h) * W_ + w0 + w) * CIN + 8 * cg] = v;
        }
    }
}

// ---------------- stage 1b: weight (o,c,tap) fp32 -> (o,tap,c) bf16 ----------------
__global__ __launch_bounds__(576)
void transpose_wgt_bf16(const float* __restrict__ wgt, short* __restrict__ wgt_t) {
    const int o = blockIdx.x;
    const int t = threadIdx.x;              // 0..575
    const int c = t / 9;
    const int tap = t - c * 9;
    wgt_t[o * KTOT + tap * CIN + c] = f2bf(wgt[o * KTOT + c * 9 + tap]);
}

// ---------------- stage 2: LDS-free MFMA implicit GEMM ----------------
// block: 16 pixels x 4 batches (M=64) x 64 Cout. 2 chunks of 32 channels;
// MFMA K-step (32) == one tap. Wave wv owns M-strip rows 16wv..16wv+15,
// all 64 Cout via j=0..3.  A frag: lane (ln,hl) = 16B of NHWC row for
// m=16wv+ln, k-seg hl. B frag: 16B of wgt_t row o=16j+ln, same k-seg.
#define PIXT  16
#define BT    4
#define LDO   68    // epilogue staging stride (floats)

__global__ __launch_bounds__(256, 4)
void sconv2davg_mfma(const short* __restrict__ nhwc,
                     const short* __restrict__ wgt_t,
                     const float* __restrict__ bias,
                     const int* __restrict__ selh,
                     const int* __restrict__ selw,
                     float* __restrict__ out) {
    __shared__ float Ot[64 * LDO];          // 17.4 KB, epilogue only

    const int tid = threadIdx.x;
    const int p0  = blockIdx.x * PIXT;
    const int b0  = blockIdx.y * BT;

    const int ln = tid & 15;                // MFMA row/col within 16
    const int hl = (tid >> 4) & 3;          // k-quad (8 bf16 = 16B segment)
    const int wv = tid >> 6;                // wave id: M-strip

    // this lane's A row: m = 16*wv + ln  ->  pixel pl = m>>2, batch bl = m&3
    const int m  = 16 * wv + ln;
    const int pl = m >> 2;
    const int bl = m & 3;
    int p = p0 + pl;
    if (p > NPIX - 1) p = NPIX - 1;         // tail clamp; stores guarded
    const int y = p / OW;
    const int x = p - y * OW;
    const int ih0 = 2 * y + selh[p];
    const int iw0 = 2 * x + selw[p];

    // base of this lane's NHWC input row (tap 0,0), in shorts
    const short* __restrict__ arow =
        nhwc + (((size_t)(b0 + bl) * H_ + ih0) * W_ + iw0) * CIN;
    // base of this lane's weight rows: o = 16*j + ln
    const short* __restrict__ wrow = wgt_t + (size_t)ln * KTOT;

    float4v acc[4];
#pragma unroll
    for (int j = 0; j < 4; ++j) acc[j] = (float4v){0.f, 0.f, 0.f, 0.f};

#pragma unroll
    for (int cc = 0; cc < 2; ++cc) {
        const int co = cc * 32 + hl * 8;    // channel offset of this lane's 16B
#pragma unroll
        for (int tap = 0; tap < 9; ++tap) {
            const int kh = tap / 3, kw = tap - 3 * (tap / 3);
            const short8 a = *(const short8*)&arow[(kh * W_ + kw) * CIN + co];
#pragma unroll
            for (int j = 0; j < 4; ++j) {
                const short8 b = *(const short8*)
                    &wrow[(size_t)(16 * j) * KTOT + tap * CIN + co];
                acc[j] = __builtin_amdgcn_mfma_f32_16x16x32_bf16(a, b, acc[j], 0, 0, 0);
            }
        }
    }

    // epilogue: C/D layout col=ln, row=4*hl+r -> LDS -> 16-consecutive-p rows
#pragma unroll
    for (int j = 0; j < 4; ++j) {
        const float bv = bias[16 * j + ln];
#pragma unroll
        for (int r = 0; r < 4; ++r)
            Ot[(16 * wv + 4 * hl + r) * LDO + 16 * j + ln] = acc[j][r] + bv;
    }
    __syncthreads();
    {
        const int o  = tid & 63;
        const int b2 = tid >> 6;
        const int rowbase = ((b0 + b2) * COUT + o) * NPIX;
#pragma unroll
        for (int pp = 0; pp < PIXT; ++pp) {
            const int pw = p0 + pp;
            if (pw < NPIX)
                out[rowbase + pw] = Ot[(pp * 4 + b2) * LDO + o];
        }
    }
}

// ---------------- fallback (round-1 kernel) if ws too small ----------------
#define FKC   72
#define FLDA  76
__global__ __launch_bounds__(256, 4)
void sconv2davg_fallback(const float* __restrict__ in,
                         const float* __restrict__ wgt,
                         const float* __restrict__ bias,
                         const int* __restrict__ selh,
                         const int* __restrict__ selw,
                         float* __restrict__ out) {
    __shared__ float As[64 * FLDA];
    __shared__ float Ws[64 * FLDA];
    __shared__ int hb_s[4], wb_s[4];
    const int tid = threadIdx.x;
    const int p0  = blockIdx.x * 4;
    if (tid < 4) {
        int p = p0 + tid;
        if (p > NPIX - 1) p = NPIX - 1;
        int y = p / OW;
        int x = p - y * OW;
        hb_s[tid] = 2 * y + selh[p];
        wb_s[tid] = 2 * x + selw[p];
    }
    __syncthreads();
    const int tn = tid & 15, tm = tid >> 4;
    float acc[4][4];
#pragma unroll
    for (int i = 0; i < 4; ++i)
#pragma unroll
        for (int j = 0; j < 4; ++j) acc[i][j] = 0.0f;
    for (int cc = 0; cc < 8; ++cc) {
        const int c0 = cc * 8;
#pragma unroll
        for (int it = 0; it < 18; ++it) {
            int idx = tid + it * 256;
            int m = idx / FKC, rem = idx - m * FKC;
            int cl = rem / 9, r = rem - cl * 9;
            int kh = r / 3, kw = r - kh * 3;
            As[m * FLDA + rem] =
                in[((((m & 15) * CIN) + (c0 + cl)) * H_ + hb_s[m >> 4] + kh) * W_ + wb_s[m >> 4] + kw];
        }
#pragma unroll
        for (int it = 0; it < 18; ++it) {
            int idx = tid + it * 256;
            int o = idx / FKC, kk = idx - o * FKC;
            Ws[o * FLDA + kk] = wgt[o * KTOT + cc * FKC + kk];
        }
        __syncthreads();
#pragma unroll 2
        for (int k0 = 0; k0 < FKC; k0 += 4) {
            float4 a[4], w[4];
#pragma unroll
            for (int i = 0; i < 4; ++i) a[i] = *(const float4*)&As[(4 * tm + i) * FLDA + k0];
#pragma unroll
            for (int j = 0; j < 4; ++j) w[j] = *(const float4*)&Ws[(tn + 16 * j) * FLDA + k0];
#pragma unroll
            for (int i = 0; i < 4; ++i)
#pragma unroll
                for (int j = 0; j < 4; ++j) {
                    acc[i][j] += a[i].x * w[j].x; acc[i][j] += a[i].y * w[j].y;
                    acc[i][j] += a[i].z * w[j].z; acc[i][j] += a[i].w * w[j].w;
                }
        }
        __syncthreads();
    }
    const int p = p0 + (tm >> 2);
    if (p < NPIX) {
#pragma unroll
        for (int i = 0; i < 4; ++i) {
            int b = (tm & 3) * 4 + i;
#pragma unroll
            for (int j = 0; j < 4; ++j)
                out[((b * COUT) + tn + 16 * j) * NPIX + p] = acc[i][j] + bias[tn + 16 * j];
        }
    }
}

extern "C" void kernel_launch(void* const* d_in, const int* in_sizes, int n_in,
                              void* d_out, int out_size, void* d_ws, size_t ws_size,
                              hipStream_t stream) {
    const float* in   = (const float*)d_in[0];
    const float* wgt  = (const float*)d_in[1];
    const float* bias = (const float*)d_in[2];
    const int*   selh = (const int*)d_in[3];
    const int*   selw = (const int*)d_in[4];
    float* out = (float*)d_out;

    const size_t nhwc_elems = (size_t)B_ * H_ * W_ * CIN;            // 16.7M bf16
    const size_t need = (nhwc_elems + (size_t)COUT * KTOT) * 2;      // ~33.6 MB

    if (ws_size >= need) {
        short* nhwc  = (short*)d_ws;
        short* wgt_t = nhwc + nhwc_elems;
        transpose_nhwc_bf16<<<dim3(W_ / 64, H_, B_), 256, 0, stream>>>(in, nhwc);
        transpose_wgt_bf16<<<COUT, 576, 0, stream>>>(wgt, wgt_t);
        const int ptiles = (NPIX + PIXT - 1) / PIXT;                 // 249
        sconv2davg_mfma<<<dim3(ptiles, B_ / BT), 256, 0, stream>>>(
            nhwc, wgt_t, bias, selh, selw, out);
    } else {
        sconv2davg_fallback<<<(NPIX + 3) / 4, 256, 0, stream>>>(
            in, wgt, bias, selh, selw, out);
    }
}

// Round 5
// 150.062 us; speedup vs baseline: 1.0958x; 1.0958x over previous
//
#include <hip/hip_runtime.h>

// SConv2dAvg: out[b,o,y,x] = sum_{c,kh,kw} in[b,c,2y+selh+kh,2x+selw+kw] * W[o,c,kh,kw] + bias[o]
// B=16 Cin=64 H=W=128 Cout=64 oh=ow=63 stride=2, fp32 in/out.
// Round 5: stage1 = NCHW->NHWC bf16 repack. Stage2 = mfma_f32_32x32x16_bf16
// implicit GEMM: W staged ONCE to LDS (conflict-free [kseg][o] layout, no
// K-loop barriers), A fragments preloaded to a 36-deep register pipeline
// (direct 16B global loads from fragment-contiguous NHWC). Dual accumulators.

#define B_    16
#define CIN   64
#define H_    128
#define W_    128
#define COUT  64
#define OH    63
#define OW    63
#define NPIX  (OH * OW)      // 3969
#define KTOT  (CIN * 9)      // 576

typedef short  short8   __attribute__((ext_vector_type(8)));
typedef float  floatx16 __attribute__((ext_vector_type(16)));

__device__ inline short f2bf(float f) {     // RN-to-even fp32 -> bf16 bits
    union { float f; unsigned u; } x; x.f = f;
    unsigned r = x.u + 0x7fffu + ((x.u >> 16) & 1u);
    return (short)(r >> 16);
}

// ---------------- stage 1a: input NCHW fp32 -> NHWC bf16 ----------------
__global__ __launch_bounds__(256)
void transpose_nhwc_bf16(const float* __restrict__ in, short* __restrict__ nhwc) {
    __shared__ float T[64 * 65];            // T[c][w], pad 65
    const int tid = threadIdx.x;
    const int w0  = blockIdx.x * 64;
    const int h   = blockIdx.y;
    const int b   = blockIdx.z;

    {   // load 64c x 64w, coalesced along w
        const int w4 = tid & 15;
        const int cl = tid >> 4;
#pragma unroll
        for (int i = 0; i < 4; ++i) {
            const int c = cl + 16 * i;
            const float4 v = *(const float4*)&in[((b * CIN + c) * H_ + h) * W_ + w0 + 4 * w4];
            T[c * 65 + 4 * w4 + 0] = v.x;
            T[c * 65 + 4 * w4 + 1] = v.y;
            T[c * 65 + 4 * w4 + 2] = v.z;
            T[c * 65 + 4 * w4 + 3] = v.w;
        }
    }
    __syncthreads();
    {   // store: 8 channels/thread as one 16B bf16 vector, coalesced along c
        const int cg = tid & 7;             // channel group (8 ch)
        const int wl = tid >> 3;            // 0..31
#pragma unroll
        for (int i = 0; i < 2; ++i) {
            const int w = wl + 32 * i;
            short8 v;
#pragma unroll
            for (int t = 0; t < 8; ++t)
                v[t] = f2bf(T[(8 * cg + t) * 65 + w]);
            *(short8*)&nhwc[((b * H_ + h) * W_ + w0 + w) * CIN + 8 * cg] = v;
        }
    }
}

// ---------------- stage 1b: weight (o,c,tap) fp32 -> (o,tap,c) bf16 ----------------
__global__ __launch_bounds__(576)
void transpose_wgt_bf16(const float* __restrict__ wgt, short* __restrict__ wgt_t) {
    const int o = blockIdx.x;
    const int t = threadIdx.x;              // 0..575
    const int c = t / 9;
    const int tap = t - c * 9;
    wgt_t[o * KTOT + tap * CIN + c] = f2bf(wgt[o * KTOT + c * 9 + tap]);
}

// ---------------- stage 2: MFMA implicit GEMM (32x32x16) ----------------
// block: 16 pixels x 4 batches (M=64) x 64 Cout. 4 waves = 2x2 grid of
// 32x32 tiles. K = 576 = 36 steps of 16 (tap-major, channels inner).
// W LDS layout: WL[g][o][8ch] (g = kseg 0..71, 16B units) -> ds_read_b128
// with consecutive-o lanes = conflict-free. A: per lane 36 x 16B direct
// global loads from NHWC, preissued as a register pipeline.
#define PIXT  16
#define BT    4
#define LDO   68    // epilogue staging stride (floats)

__global__ __launch_bounds__(256, 2)
void sconv2davg_mfma(const short* __restrict__ nhwc,
                     const short* __restrict__ wgt_t,
                     const float* __restrict__ bias,
                     const int* __restrict__ selh,
                     const int* __restrict__ selw,
                     float* __restrict__ out) {
    __shared__ __align__(16) short WL[72 * 64 * 8];   // 73728 B; reused as Ot

    const int tid = threadIdx.x;
    const int p0  = blockIdx.x * PIXT;
    const int b0  = blockIdx.y * BT;

    const int lane = tid & 63;
    const int wv   = tid >> 6;
    const int ln32 = lane & 31;             // MFMA row/col within 32
    const int h    = lane >> 5;             // k-half (8 of 16)
    const int mw   = wv & 1;                // M-tile: rows 32*mw..+31
    const int nw   = wv >> 1;               // N-tile: cols 32*nw..+31
    const int m0   = mw * 32;
    const int o0   = nw * 32;

    // ---- stage W into LDS: 4608 16B chunks, 18 per thread ----
#pragma unroll
    for (int i = 0; i < 18; ++i) {
        const int idx = i * 256 + tid;
        const int o   = idx & 63;
        const int g   = idx >> 6;           // 0..71
        *(short8*)&WL[(g * 64 + o) * 8] = *(const short8*)&wgt_t[o * KTOT + g * 8];
    }

    // ---- this lane's A row ----
    const int m  = m0 + ln32;               // 0..63
    const int pl = m >> 2;
    const int bl = m & 3;
    int p = p0 + pl;
    if (p > NPIX - 1) p = NPIX - 1;         // tail clamp; stores guarded
    const int y = p / OW;
    const int x = p - y * OW;
    const int ih0 = 2 * y + selh[p];
    const int iw0 = 2 * x + selw[p];
    const short* __restrict__ arow =
        nhwc + (((size_t)(b0 + bl) * H_ + ih0) * W_ + iw0) * CIN;

    __syncthreads();                        // W staged

    // ---- preload all 36 A fragments (register pipeline) ----
    short8 areg[36];
#pragma unroll
    for (int tap = 0; tap < 9; ++tap) {
        const int kh = tap / 3, kw = tap - 3 * (tap / 3);
#pragma unroll
        for (int q = 0; q < 4; ++q)
            areg[tap * 4 + q] = *(const short8*)&arow[(kh * W_ + kw) * CIN + q * 16 + h * 8];
    }

    // ---- K loop: 36 steps, 1 ds_read + 1 MFMA each, no barriers ----
    floatx16 acc0 = {0.f}, acc1 = {0.f};
#pragma unroll
    for (int s = 0; s < 36; s += 2) {
        const short8 b0f = *(const short8*)&WL[(((s + 0) * 2 + h) * 64 + o0 + ln32) * 8];
        acc0 = __builtin_amdgcn_mfma_f32_32x32x16_bf16(areg[s + 0], b0f, acc0, 0, 0, 0);
        const short8 b1f = *(const short8*)&WL[(((s + 1) * 2 + h) * 64 + o0 + ln32) * 8];
        acc1 = __builtin_amdgcn_mfma_f32_32x32x16_bf16(areg[s + 1], b1f, acc1, 0, 0, 0);
    }

    __syncthreads();                        // all WL reads done; reuse as Ot

    // ---- epilogue: C/D layout col=ln32, row=(r&3)+8*(r>>2)+4*h ----
    float* Ot = (float*)WL;
    const float bv = bias[o0 + ln32];
#pragma unroll
    for (int r = 0; r < 16; ++r) {
        const int row = (r & 3) + 8 * (r >> 2) + 4 * h;
        Ot[(m0 + row) * LDO + o0 + ln32] = acc0[r] + acc1[r] + bv;
    }
    __syncthreads();
    {
        const int o  = tid & 63;
        const int b2 = tid >> 6;
        const int rowbase = ((b0 + b2) * COUT + o) * NPIX;
#pragma unroll
        for (int pp = 0; pp < PIXT; ++pp) {
            const int pw = p0 + pp;
            if (pw < NPIX)
                out[rowbase + pw] = Ot[(pp * 4 + b2) * LDO + o];
        }
    }
}

// ---------------- fallback (round-1 kernel) if ws too small ----------------
#define FKC   72
#define FLDA  76
__global__ __launch_bounds__(256, 4)
void sconv2davg_fallback(const float* __restrict__ in,
                         const float* __restrict__ wgt,
                         const float* __restrict__ bias,
                         const int* __restrict__ selh,
                         const int* __restrict__ selw,
                         float* __restrict__ out) {
    __shared__ float As[64 * FLDA];
    __shared__ float Ws[64 * FLDA];
    __shared__ int hb_s[4], wb_s[4];
    const int tid = threadIdx.x;
    const int p0  = blockIdx.x * 4;
    if (tid < 4) {
        int p = p0 + tid;
        if (p > NPIX - 1) p = NPIX - 1;
        int y = p / OW;
        int x = p - y * OW;
        hb_s[tid] = 2 * y + selh[p];
        wb_s[tid] = 2 * x + selw[p];
    }
    __syncthreads();
    const int tn = tid & 15, tm = tid >> 4;
    float acc[4][4];
#pragma unroll
    for (int i = 0; i < 4; ++i)
#pragma unroll
        for (int j = 0; j < 4; ++j) acc[i][j] = 0.0f;
    for (int cc = 0; cc < 8; ++cc) {
        const int c0 = cc * 8;
#pragma unroll
        for (int it = 0; it < 18; ++it) {
            int idx = tid + it * 256;
            int m = idx / FKC, rem = idx - m * FKC;
            int cl = rem / 9, r = rem - cl * 9;
            int kh = r / 3, kw = r - kh * 3;
            As[m * FLDA + rem] =
                in[((((m & 15) * CIN) + (c0 + cl)) * H_ + hb_s[m >> 4] + kh) * W_ + wb_s[m >> 4] + kw];
        }
#pragma unroll
        for (int it = 0; it < 18; ++it) {
            int idx = tid + it * 256;
            int o = idx / FKC, kk = idx - o * FKC;
            Ws[o * FLDA + kk] = wgt[o * KTOT + cc * FKC + kk];
        }
        __syncthreads();
#pragma unroll 2
        for (int k0 = 0; k0 < FKC; k0 += 4) {
            float4 a[4], w[4];
#pragma unroll
            for (int i = 0; i < 4; ++i) a[i] = *(const float4*)&As[(4 * tm + i) * FLDA + k0];
#pragma unroll
            for (int j = 0; j < 4; ++j) w[j] = *(const float4*)&Ws[(tn + 16 * j) * FLDA + k0];
#pragma unroll
            for (int i = 0; i < 4; ++i)
#pragma unroll
                for (int j = 0; j < 4; ++j) {
                    acc[i][j] += a[i].x * w[j].x; acc[i][j] += a[i].y * w[j].y;
                    acc[i][j] += a[i].z * w[j].z; acc[i][j] += a[i].w * w[j].w;
                }
        }
        __syncthreads();
    }
    const int p = p0 + (tm >> 2);
    if (p < NPIX) {
#pragma unroll
        for (int i = 0; i < 4; ++i) {
            int b = (tm & 3) * 4 + i;
#pragma unroll
            for (int j = 0; j < 4; ++j)
                out[((b * COUT) + tn + 16 * j) * NPIX + p] = acc[i][j] + bias[tn + 16 * j];
        }
    }
}

extern "C" void kernel_launch(void* const* d_in, const int* in_sizes, int n_in,
                              void* d_out, int out_size, void* d_ws, size_t ws_size,
                              hipStream_t stream) {
    const float* in   = (const float*)d_in[0];
    const float* wgt  = (const float*)d_in[1];
    const float* bias = (const float*)d_in[2];
    const int*   selh = (const int*)d_in[3];
    const int*   selw = (const int*)d_in[4];
    float* out = (float*)d_out;

    const size_t nhwc_elems = (size_t)B_ * H_ * W_ * CIN;            // 16.7M bf16
    const size_t need = (nhwc_elems + (size_t)COUT * KTOT) * 2;      // ~33.6 MB

    if (ws_size >= need) {
        short* nhwc  = (short*)d_ws;
        short* wgt_t = nhwc + nhwc_elems;
        transpose_nhwc_bf16<<<dim3(W_ / 64, H_, B_), 256, 0, stream>>>(in, nhwc);
        transpose_wgt_bf16<<<COUT, 576, 0, stream>>>(wgt, wgt_t);
        const int ptiles = (NPIX + PIXT - 1) / PIXT;                 // 249
        sconv2davg_mfma<<<dim3(ptiles, B_ / BT), 256, 0, stream>>>(
            nhwc, wgt_t, bias, selh, selw, out);
    } else {
        sconv2davg_fallback<<<(NPIX + 3) / 4, 256, 0, stream>>>(
            in, wgt, bias, selh, selw, out);
    }
}